// Round 9
// baseline (389.054 us; speedup 1.0000x reference)
//
#include <hip/hip_runtime.h>

#define FDIM 64

typedef unsigned short u16;

__device__ __forceinline__ u16 f2bf(float x) {          // RNE f32->bf16
    unsigned int u = __float_as_uint(x);
    return (u16)((u + 0x7fff + ((u >> 16) & 1)) >> 16);
}
__device__ __forceinline__ float2 up2(unsigned int u) { // 2 packed bf16 -> 2 f32
    float2 r;
    r.x = __uint_as_float(u << 16);
    r.y = __uint_as_float(u & 0xffff0000u);
    return r;
}

// ========= dense tile body: t[64 rows] = act(ain + bias) @ W  (bf16 out) ====
// W in LDS (16 KB only -> full wave occupancy); A rows read direct from
// global as float4 (16 threads/row -> L1 broadcast). 4 rows x 4 cols/thread.

__device__ __forceinline__ void mm_body(
    const float* __restrict__ ain, const float* __restrict__ bias,
    int do_relu, u16* __restrict__ t, int n, int blk,
    const float4* __restrict__ Ws4s)
{
    int tid = threadIdx.x;
    int r0 = blk * 64;
    int rq = tid >> 4, cq = tid & 15;
    int R[4];
    #pragma unroll
    for (int i = 0; i < 4; ++i) R[i] = r0 + rq * 4 + i;

    float acc[4][4];
    #pragma unroll
    for (int i = 0; i < 4; ++i)
        #pragma unroll
        for (int j = 0; j < 4; ++j) acc[i][j] = 0.f;

    const float4* A4 = (const float4*)ain;
    #pragma unroll 4
    for (int kq = 0; kq < 16; ++kq) {
        float4 bv = make_float4(0.f, 0.f, 0.f, 0.f);
        if (bias != nullptr) bv = ((const float4*)bias)[kq];
        float av[4][4];
        #pragma unroll
        for (int i = 0; i < 4; ++i) {
            float4 a = make_float4(0.f, 0.f, 0.f, 0.f);
            if (R[i] < n) a = A4[(size_t)R[i] * 16 + kq];
            a.x += bv.x; a.y += bv.y; a.z += bv.z; a.w += bv.w;
            if (do_relu) {
                a.x = fmaxf(a.x, 0.f); a.y = fmaxf(a.y, 0.f);
                a.z = fmaxf(a.z, 0.f); a.w = fmaxf(a.w, 0.f);
            }
            av[i][0] = a.x; av[i][1] = a.y; av[i][2] = a.z; av[i][3] = a.w;
        }
        #pragma unroll
        for (int j = 0; j < 4; ++j) {
            float4 w = Ws4s[(kq * 4 + j) * 16 + cq];
            #pragma unroll
            for (int i = 0; i < 4; ++i) {
                acc[i][0] = fmaf(av[i][j], w.x, acc[i][0]);
                acc[i][1] = fmaf(av[i][j], w.y, acc[i][1]);
                acc[i][2] = fmaf(av[i][j], w.z, acc[i][2]);
                acc[i][3] = fmaf(av[i][j], w.w, acc[i][3]);
            }
        }
    }

    #pragma unroll
    for (int i = 0; i < 4; ++i) {
        if (R[i] < n) {
            ushort4 o;
            o.x = f2bf(acc[i][0]); o.y = f2bf(acc[i][1]);
            o.z = f2bf(acc[i][2]); o.w = f2bf(acc[i][3]);
            ((ushort4*)t)[(size_t)R[i] * 16 + cq] = o;
        }
    }
}

__global__ __launch_bounds__(256) void k_matmul(
    const float* __restrict__ ain, const float* __restrict__ Wm,
    const float* __restrict__ bias, int do_relu,
    u16* __restrict__ t, int n)
{
    __shared__ float4 Ws4s[1024];
    int tid = threadIdx.x;
    #pragma unroll
    for (int i = 0; i < 4; ++i) Ws4s[tid + 256 * i] = ((const float4*)Wm)[tid + 256 * i];
    __syncthreads();
    mm_body(ain, bias, do_relu, t, n, blockIdx.x, Ws4s);
}

// ===== combined dispatch: matmul1 blocks + XCD-partitioned CSR-fill blocks ==
// Fill is atomic-latency bound (VALUBusy ~0.5%) so matmul1 hides inside it.
// 16 KB LDS -> occupancy is wave-capped (8 blocks/CU), fill gets full waves.

__global__ __launch_bounds__(256) void k_mm_fill(
    const float* __restrict__ x, const float* __restrict__ W1,
    u16* __restrict__ t,
    const int* __restrict__ src, const int* __restrict__ dst,
    int* __restrict__ cnt, int* __restrict__ csr,
    int n, int E, int cap, int mm_blocks, int fill_chunks)
{
    __shared__ float4 Ws4s[1024];
    if ((int)blockIdx.x < mm_blocks) {
        int tid = threadIdx.x;
        #pragma unroll
        for (int i = 0; i < 4; ++i) Ws4s[tid + 256 * i] = ((const float4*)W1)[tid + 256 * i];
        __syncthreads();
        mm_body(x, nullptr, 0, t, n, blockIdx.x, Ws4s);
        return;
    }
    // fill: partition dst range by XCD (blockIdx%8 round-robin; mm_blocks %8==0)
    int gb = blockIdx.x - mm_blocks;
    int part = blockIdx.x & 7;
    int chunk = gb >> 3;
    int psz = n >> 3;
    int lo = psz * part;
    int hi = (part == 7) ? n : lo + psz;
    int per = (E + fill_chunks - 1) / fill_chunks;
    int e1 = chunk * per + per; if (e1 > E) e1 = E;
    for (int e = chunk * per + threadIdx.x; e < e1; e += 256) {
        int d = dst[e];
        if (d >= lo && d < hi) {
            int p = atomicAdd(&cnt[d], 1);
            if (p < cap) csr[(size_t)d * cap + p] = src[e];
        }
    }
}

// == aggregate: agg[i] = di*(di*t_i + sum_j dj*t_j);  di = rsqrt(deg_i+1) ==
// 2 nodes per wave: lane = (half, feature-pair). Each gather = 32 lanes x
// 4 B (2 bf16) -> two independent gather streams/wave, 16 loads in flight.

__global__ __launch_bounds__(256) void k_aggregate(
    const int* __restrict__ cnt, const int* __restrict__ csr,
    const u16* __restrict__ t, float* __restrict__ agg, int n, int cap)
{
    int tid = threadIdx.x;
    long long gw = ((long long)blockIdx.x * 256 + tid) >> 6;
    int lane = tid & 63;
    int half = lane >> 5;
    int fp = lane & 31;
    long long il = gw * 2 + half;
    if (il >= n) return;
    int i = (int)il;

    int deg = cnt[i];
    float di = rsqrtf((float)deg + 1.0f);
    int m = deg < cap ? deg : cap;
    int mm32 = m < 32 ? m : 32;

    const unsigned int* tu = (const unsigned int*)t;
    float2 a0 = up2(tu[(size_t)i * 32 + fp]);
    a0.x *= di; a0.y *= di;
    float2 a1 = make_float2(0.f, 0.f);
    float2 a2 = make_float2(0.f, 0.f);
    float2 a3 = make_float2(0.f, 0.f);

    const int* row = csr + (size_t)i * cap;
    int sv = 0; float dvv = 0.f;
    if (fp < mm32) { sv = row[fp]; dvv = rsqrtf((float)cnt[sv] + 1.0f); }

    int base = half << 5;
    int k = 0;
    for (; k + 8 <= mm32; k += 8) {
        int jv[8]; float dj[8]; unsigned int v[8];
        #pragma unroll
        for (int u = 0; u < 8; ++u) {
            jv[u] = __shfl(sv, base + k + u);
            dj[u] = __shfl(dvv, base + k + u);
        }
        #pragma unroll
        for (int u = 0; u < 8; ++u) v[u] = tu[(size_t)jv[u] * 32 + fp];
        float2 x0 = up2(v[0]), x1 = up2(v[1]), x2 = up2(v[2]), x3 = up2(v[3]);
        float2 x4 = up2(v[4]), x5 = up2(v[5]), x6 = up2(v[6]), x7 = up2(v[7]);
        a0.x = fmaf(x0.x, dj[0], a0.x); a0.y = fmaf(x0.y, dj[0], a0.y);
        a1.x = fmaf(x1.x, dj[1], a1.x); a1.y = fmaf(x1.y, dj[1], a1.y);
        a2.x = fmaf(x2.x, dj[2], a2.x); a2.y = fmaf(x2.y, dj[2], a2.y);
        a3.x = fmaf(x3.x, dj[3], a3.x); a3.y = fmaf(x3.y, dj[3], a3.y);
        a0.x = fmaf(x4.x, dj[4], a0.x); a0.y = fmaf(x4.y, dj[4], a0.y);
        a1.x = fmaf(x5.x, dj[5], a1.x); a1.y = fmaf(x5.y, dj[5], a1.y);
        a2.x = fmaf(x6.x, dj[6], a2.x); a2.y = fmaf(x6.y, dj[6], a2.y);
        a3.x = fmaf(x7.x, dj[7], a3.x); a3.y = fmaf(x7.y, dj[7], a3.y);
    }
    if (k + 4 <= mm32) {
        int jv[4]; float dj[4]; unsigned int v[4];
        #pragma unroll
        for (int u = 0; u < 4; ++u) {
            jv[u] = __shfl(sv, base + k + u);
            dj[u] = __shfl(dvv, base + k + u);
        }
        #pragma unroll
        for (int u = 0; u < 4; ++u) v[u] = tu[(size_t)jv[u] * 32 + fp];
        float2 x0 = up2(v[0]), x1 = up2(v[1]), x2 = up2(v[2]), x3 = up2(v[3]);
        a0.x = fmaf(x0.x, dj[0], a0.x); a0.y = fmaf(x0.y, dj[0], a0.y);
        a1.x = fmaf(x1.x, dj[1], a1.x); a1.y = fmaf(x1.y, dj[1], a1.y);
        a2.x = fmaf(x2.x, dj[2], a2.x); a2.y = fmaf(x2.y, dj[2], a2.y);
        a3.x = fmaf(x3.x, dj[3], a3.x); a3.y = fmaf(x3.y, dj[3], a3.y);
        k += 4;
    }
    for (; k < mm32; ++k) {
        int j = __shfl(sv, base + k);
        float dj = __shfl(dvv, base + k);
        float2 x = up2(tu[(size_t)j * 32 + fp]);
        a0.x = fmaf(x.x, dj, a0.x); a0.y = fmaf(x.y, dj, a0.y);
    }
    // rare overflow tail (deg > 32): per-lane broadcast reads
    for (int kk = 32; kk < m; ++kk) {
        int j = row[kk];
        float dj = rsqrtf((float)cnt[j] + 1.0f);
        float2 x = up2(tu[(size_t)j * 32 + fp]);
        a0.x = fmaf(x.x, dj, a0.x); a0.y = fmaf(x.y, dj, a0.y);
    }

    float2 o;
    o.x = ((a0.x + a1.x) + (a2.x + a3.x)) * di;
    o.y = ((a0.y + a1.y) + (a2.y + a3.y)) * di;
    ((float2*)agg)[(size_t)i * 32 + fp] = o;
}

// ================= pool =================

__global__ __launch_bounds__(256) void k_pool1(
    const float* __restrict__ agg, const int* __restrict__ batch,
    float* __restrict__ partial, int n)
{
    int g = blockIdx.x >> 3;
    int part = blockIdx.x & 7;
    int tid = threadIdx.x;

    int lo = 0, hi = n;
    while (lo < hi) { int mid = (lo + hi) >> 1; if (batch[mid] < g) lo = mid + 1; else hi = mid; }
    int start = lo;
    hi = n;
    while (lo < hi) { int mid = (lo + hi) >> 1; if (batch[mid] <= g) lo = mid + 1; else hi = mid; }
    int end = lo;

    int f = tid & 63, r = tid >> 6;
    float s = 0.f;
    for (int i = start + part * 4 + r; i < end; i += 32)
        s += agg[(size_t)i * 64 + f];

    __shared__ float red[4][64];
    red[r][f] = s;
    __syncthreads();
    if (tid < 64)
        partial[((size_t)g * 8 + part) * 64 + tid] =
            red[0][tid] + red[1][tid] + red[2][tid] + red[3][tid];
}

__global__ __launch_bounds__(64) void k_pool2(
    const float* __restrict__ partial, const int* __restrict__ batch,
    const float* __restrict__ b3, const float* __restrict__ Wlin,
    const float* __restrict__ blin, float* __restrict__ out,
    int n, int fout)
{
    int g = blockIdx.x;
    int tid = threadIdx.x;

    int lo = 0, hi = n;
    while (lo < hi) { int mid = (lo + hi) >> 1; if (batch[mid] < g) lo = mid + 1; else hi = mid; }
    int start = lo;
    hi = n;
    while (lo < hi) { int mid = (lo + hi) >> 1; if (batch[mid] <= g) lo = mid + 1; else hi = mid; }
    int cnt = lo - start;

    __shared__ float pooled[64];
    float v = 0.f;
    #pragma unroll
    for (int p = 0; p < 8; ++p) v += partial[((size_t)g * 8 + p) * 64 + tid];
    pooled[tid] = (cnt > 0) ? (v / (float)cnt + b3[tid]) : 0.f;
    __syncthreads();
    if (tid < fout) {
        float o = blin[tid];
        for (int k = 0; k < 64; ++k) o += pooled[k] * Wlin[k * fout + tid];
        out[(size_t)g * fout + tid] = o;
    }
}

// ================= launcher =================

extern "C" void kernel_launch(void* const* d_in, const int* in_sizes, int n_in,
                              void* d_out, int out_size, void* d_ws, size_t ws_size,
                              hipStream_t stream) {
    const float* x     = (const float*)d_in[0];
    const int*   ei    = (const int*)d_in[1];
    const int*   batch = (const int*)d_in[2];
    const float* W1 = (const float*)d_in[3];
    const float* b1 = (const float*)d_in[4];
    const float* W2 = (const float*)d_in[5];
    const float* b2 = (const float*)d_in[6];
    const float* W3 = (const float*)d_in[7];
    const float* b3 = (const float*)d_in[8];
    const float* Wl = (const float*)d_in[9];
    const float* bl = (const float*)d_in[10];

    int n = in_sizes[0] / 64;
    int E = in_sizes[1] / 2;
    int fout = in_sizes[10];
    int ngraphs = out_size / fout;

    const int* srcp = ei;
    const int* dstp = ei + E;

    // ws layout: agg f32 | t bf16 | partial | cnt | csr
    float* ws   = (float*)d_ws;
    float* agg  = ws;                              // n*64 f32
    u16*   t    = (u16*)(agg + (size_t)n * 64);    // n*64 bf16
    float* partial = (float*)(t + (size_t)n * 64); // 64*8*64
    int* cnt    = (int*)(partial + 64 * 8 * 64);   // n
    int* csr    = cnt + n;                         // n*cap

    size_t fixed = (size_t)n * 64 * 4 + (size_t)n * 64 * 2 +
                   64 * 8 * 64 * 4 + (size_t)n * 4;
    int cap = 64;
    while (cap > 32 && fixed + (size_t)n * cap * 4 > ws_size) cap -= 8;
    // avg degree E/n ~10 (Poisson); max degree ~25 -> cap>=32 is safe.

    int nb_ag = (int)((((long long)(n + 1) / 2) * 64 + 255) / 256);
    int mm_blocks = (((n + 63) / 64 + 7) / 8) * 8;   // multiple of 8
    int fill_chunks = 128;                            // 8 parts x 128 = 1024 blocks

    hipMemsetAsync(cnt, 0, (size_t)n * sizeof(int), stream);
    // t1 = x @ W1 (bf16) + CSR build, overlapped in one dispatch
    k_mm_fill<<<mm_blocks + 8 * fill_chunks, 256, 0, stream>>>(
        x, W1, t, srcp, dstp, cnt, csr, n, E, cap, mm_blocks, fill_chunks);

    // layer 1 aggregate
    k_aggregate<<<nb_ag, 256, 0, stream>>>(cnt, csr, t, agg, n, cap);
    // layer 2
    k_matmul<<<mm_blocks, 256, 0, stream>>>(agg, W2, b1, 1, t, n);
    k_aggregate<<<nb_ag, 256, 0, stream>>>(cnt, csr, t, agg, n, cap);
    // layer 3
    k_matmul<<<mm_blocks, 256, 0, stream>>>(agg, W3, b2, 1, t, n);
    k_aggregate<<<nb_ag, 256, 0, stream>>>(cnt, csr, t, agg, n, cap);

    // pool + linear
    k_pool1<<<ngraphs * 8, 256, 0, stream>>>(agg, batch, partial, n);
    k_pool2<<<ngraphs, 64, 0, stream>>>(partial, batch, b3, Wl, bl, (float*)d_out, n, fout);
}

// Round 10
// 296.955 us; speedup vs baseline: 1.3101x; 1.3101x over previous
//
#include <hip/hip_runtime.h>

#define FDIM 64

typedef unsigned short u16;

__device__ __forceinline__ u16 f2bf(float x) {          // RNE f32->bf16
    unsigned int u = __float_as_uint(x);
    return (u16)((u + 0x7fff + ((u >> 16) & 1)) >> 16);
}
__device__ __forceinline__ float bf2f(u16 h) {
    return __uint_as_float(((unsigned int)h) << 16);
}
__device__ __forceinline__ float2 up2(unsigned int u) { // 2 packed bf16 -> 2 f32
    float2 r;
    r.x = __uint_as_float(u << 16);
    r.y = __uint_as_float(u & 0xffff0000u);
    return r;
}

// ========= dense tile: t[64 rows] = act(ain + bias) @ W  (bf16 out) =========
// R8 structure (known-good 52 VGPR): A staged to LDS f32, W in LDS.
// BF16IN: A is bf16 (the in-place bf16 agg); else f32.

template <bool BF16IN>
__device__ __forceinline__ void mm_tile64(
    const void* __restrict__ ain, const float* __restrict__ bias, int do_relu,
    u16* __restrict__ t, int n, int blk,
    float (*__restrict__ As)[FDIM + 1], float* __restrict__ Ws)
{
    int tid = threadIdx.x;
    int r0 = blk * 64;

    #pragma unroll
    for (int i = 0; i < 4; ++i) {
        int idx = tid + 256 * i;
        int r = idx >> 4;
        int kq = idx & 15;
        float4 v = make_float4(0.f, 0.f, 0.f, 0.f);
        int R = r0 + r;
        if (R < n) {
            if (BF16IN) {
                ushort4 h = ((const ushort4*)ain)[(size_t)R * 16 + kq];
                v.x = bf2f(h.x); v.y = bf2f(h.y); v.z = bf2f(h.z); v.w = bf2f(h.w);
            } else {
                v = ((const float4*)ain)[(size_t)R * 16 + kq];
            }
            if (bias != nullptr) {
                float4 b = ((const float4*)bias)[kq];
                v.x += b.x; v.y += b.y; v.z += b.z; v.w += b.w;
            }
            if (do_relu) {
                v.x = fmaxf(v.x, 0.f); v.y = fmaxf(v.y, 0.f);
                v.z = fmaxf(v.z, 0.f); v.w = fmaxf(v.w, 0.f);
            }
        }
        As[r][kq * 4 + 0] = v.x;
        As[r][kq * 4 + 1] = v.y;
        As[r][kq * 4 + 2] = v.z;
        As[r][kq * 4 + 3] = v.w;
    }
    __syncthreads();

    int rq = tid >> 4;   // rows rq*4..+3
    int cq = tid & 15;   // cols cq*4..+3
    float acc[4][4];
    #pragma unroll
    for (int i = 0; i < 4; ++i)
        #pragma unroll
        for (int j = 0; j < 4; ++j) acc[i][j] = 0.f;

    const float4* Ws4 = (const float4*)Ws;
    #pragma unroll 4
    for (int k = 0; k < FDIM; ++k) {
        float4 w = Ws4[k * 16 + cq];
        float a[4];
        #pragma unroll
        for (int i = 0; i < 4; ++i) a[i] = As[rq * 4 + i][k];
        #pragma unroll
        for (int i = 0; i < 4; ++i) {
            acc[i][0] = fmaf(a[i], w.x, acc[i][0]);
            acc[i][1] = fmaf(a[i], w.y, acc[i][1]);
            acc[i][2] = fmaf(a[i], w.z, acc[i][2]);
            acc[i][3] = fmaf(a[i], w.w, acc[i][3]);
        }
    }

    #pragma unroll
    for (int i = 0; i < 4; ++i) {
        int R = r0 + rq * 4 + i;
        if (R < n) {
            ushort4 o;
            o.x = f2bf(acc[i][0]); o.y = f2bf(acc[i][1]);
            o.z = f2bf(acc[i][2]); o.w = f2bf(acc[i][3]);
            ((ushort4*)t)[(size_t)R * 16 + cq] = o;
        }
    }
}

// layers 2/3: A = bf16 agg
__global__ __launch_bounds__(256) void k_matmul_h(
    const u16* __restrict__ ain, const float* __restrict__ Wm,
    const float* __restrict__ bias, u16* __restrict__ t, int n)
{
    __shared__ float As[64][FDIM + 1];
    __shared__ float Ws[FDIM * FDIM];
    int tid = threadIdx.x;
    #pragma unroll
    for (int i = 0; i < 4; ++i)
        ((float4*)Ws)[tid + 256 * i] = ((const float4*)Wm)[tid + 256 * i];
    mm_tile64<true>(ain, bias, 1, t, n, blockIdx.x, As, Ws);
}

// ===== combined dispatch: matmul1 blocks + XCD-partitioned CSR-fill blocks ==

__global__ __launch_bounds__(256) void k_mm_fill(
    const float* __restrict__ x, const float* __restrict__ W1,
    u16* __restrict__ t,
    const int* __restrict__ src, const int* __restrict__ dst,
    int* __restrict__ cnt, int* __restrict__ csr,
    int n, int E, int cap, int mm_blocks, int fill_chunks)
{
    __shared__ float As[64][FDIM + 1];
    __shared__ float Ws[FDIM * FDIM];

    if ((int)blockIdx.x < mm_blocks) {
        int tid = threadIdx.x;
        #pragma unroll
        for (int i = 0; i < 4; ++i)
            ((float4*)Ws)[tid + 256 * i] = ((const float4*)W1)[tid + 256 * i];
        mm_tile64<false>(x, nullptr, 0, t, n, blockIdx.x, As, Ws);
        return;
    }
    // fill: partition dst range by XCD (blockIdx%8 round-robin; mm_blocks%8==0)
    int gb = blockIdx.x - mm_blocks;
    int part = blockIdx.x & 7;
    int chunk = gb >> 3;
    int psz = n >> 3;
    int lo = psz * part;
    int hi = (part == 7) ? n : lo + psz;
    int per = (E + fill_chunks - 1) / fill_chunks;
    int e1 = chunk * per + per; if (e1 > E) e1 = E;
    for (int e = chunk * per + threadIdx.x; e < e1; e += 256) {
        int d = dst[e];
        if (d >= lo && d < hi) {
            int p = atomicAdd(&cnt[d], 1);
            if (p < cap)
                __builtin_nontemporal_store(src[e], &csr[(size_t)d * cap + p]);
        }
    }
}

// == aggregate: out[i] = di*(di*t_i + sum_j dj*t_j);  di = rsqrt(deg_i+1) ==
// 2 nodes per wave: lane = (half, feature-pair); 16 gather streams/wave.
// OUTF32: write f32 (last layer, feeds pool); else packed bf16 in-place.

__global__ __launch_bounds__(256) void k_aggregate(
    const int* __restrict__ cnt, const int* __restrict__ csr,
    const u16* __restrict__ t, float* __restrict__ aggf,
    unsigned int* __restrict__ aggh, int outf32, int n, int cap)
{
    int tid = threadIdx.x;
    long long gw = ((long long)blockIdx.x * 256 + tid) >> 6;
    int lane = tid & 63;
    int half = lane >> 5;
    int fp = lane & 31;
    long long il = gw * 2 + half;
    if (il >= n) return;
    int i = (int)il;

    int deg = cnt[i];
    float di = rsqrtf((float)deg + 1.0f);
    int m = deg < cap ? deg : cap;
    int mm32 = m < 32 ? m : 32;

    const unsigned int* tu = (const unsigned int*)t;
    float2 a0 = up2(tu[(size_t)i * 32 + fp]);
    a0.x *= di; a0.y *= di;
    float2 a1 = make_float2(0.f, 0.f);
    float2 a2 = make_float2(0.f, 0.f);
    float2 a3 = make_float2(0.f, 0.f);

    const int* row = csr + (size_t)i * cap;
    int sv = 0; float dvv = 0.f;
    if (fp < mm32) { sv = row[fp]; dvv = rsqrtf((float)cnt[sv] + 1.0f); }

    int base = half << 5;
    int k = 0;
    for (; k + 8 <= mm32; k += 8) {
        int jv[8]; float dj[8]; unsigned int v[8];
        #pragma unroll
        for (int u = 0; u < 8; ++u) {
            jv[u] = __shfl(sv, base + k + u);
            dj[u] = __shfl(dvv, base + k + u);
        }
        #pragma unroll
        for (int u = 0; u < 8; ++u) v[u] = tu[(size_t)jv[u] * 32 + fp];
        float2 x0 = up2(v[0]), x1 = up2(v[1]), x2 = up2(v[2]), x3 = up2(v[3]);
        float2 x4 = up2(v[4]), x5 = up2(v[5]), x6 = up2(v[6]), x7 = up2(v[7]);
        a0.x = fmaf(x0.x, dj[0], a0.x); a0.y = fmaf(x0.y, dj[0], a0.y);
        a1.x = fmaf(x1.x, dj[1], a1.x); a1.y = fmaf(x1.y, dj[1], a1.y);
        a2.x = fmaf(x2.x, dj[2], a2.x); a2.y = fmaf(x2.y, dj[2], a2.y);
        a3.x = fmaf(x3.x, dj[3], a3.x); a3.y = fmaf(x3.y, dj[3], a3.y);
        a0.x = fmaf(x4.x, dj[4], a0.x); a0.y = fmaf(x4.y, dj[4], a0.y);
        a1.x = fmaf(x5.x, dj[5], a1.x); a1.y = fmaf(x5.y, dj[5], a1.y);
        a2.x = fmaf(x6.x, dj[6], a2.x); a2.y = fmaf(x6.y, dj[6], a2.y);
        a3.x = fmaf(x7.x, dj[7], a3.x); a3.y = fmaf(x7.y, dj[7], a3.y);
    }
    if (k + 4 <= mm32) {
        int jv[4]; float dj[4]; unsigned int v[4];
        #pragma unroll
        for (int u = 0; u < 4; ++u) {
            jv[u] = __shfl(sv, base + k + u);
            dj[u] = __shfl(dvv, base + k + u);
        }
        #pragma unroll
        for (int u = 0; u < 4; ++u) v[u] = tu[(size_t)jv[u] * 32 + fp];
        float2 x0 = up2(v[0]), x1 = up2(v[1]), x2 = up2(v[2]), x3 = up2(v[3]);
        a0.x = fmaf(x0.x, dj[0], a0.x); a0.y = fmaf(x0.y, dj[0], a0.y);
        a1.x = fmaf(x1.x, dj[1], a1.x); a1.y = fmaf(x1.y, dj[1], a1.y);
        a2.x = fmaf(x2.x, dj[2], a2.x); a2.y = fmaf(x2.y, dj[2], a2.y);
        a3.x = fmaf(x3.x, dj[3], a3.x); a3.y = fmaf(x3.y, dj[3], a3.y);
        k += 4;
    }
    for (; k < mm32; ++k) {
        int j = __shfl(sv, base + k);
        float dj = __shfl(dvv, base + k);
        float2 xx = up2(tu[(size_t)j * 32 + fp]);
        a0.x = fmaf(xx.x, dj, a0.x); a0.y = fmaf(xx.y, dj, a0.y);
    }
    // rare overflow tail (deg > 32)
    for (int kk = 32; kk < m; ++kk) {
        int j = row[kk];
        float dj = rsqrtf((float)cnt[j] + 1.0f);
        float2 xx = up2(tu[(size_t)j * 32 + fp]);
        a0.x = fmaf(xx.x, dj, a0.x); a0.y = fmaf(xx.y, dj, a0.y);
    }

    float ox = ((a0.x + a1.x) + (a2.x + a3.x)) * di;
    float oy = ((a0.y + a1.y) + (a2.y + a3.y)) * di;
    if (outf32) {
        ((float2*)aggf)[(size_t)i * 32 + fp] = make_float2(ox, oy);
    } else {
        unsigned int pk = ((unsigned int)f2bf(ox)) | (((unsigned int)f2bf(oy)) << 16);
        aggh[(size_t)i * 32 + fp] = pk;
    }
}

// ================= pool =================

__global__ __launch_bounds__(256) void k_pool1(
    const float* __restrict__ agg, const int* __restrict__ batch,
    float* __restrict__ partial, int n)
{
    int g = blockIdx.x >> 3;
    int part = blockIdx.x & 7;
    int tid = threadIdx.x;

    int lo = 0, hi = n;
    while (lo < hi) { int mid = (lo + hi) >> 1; if (batch[mid] < g) lo = mid + 1; else hi = mid; }
    int start = lo;
    hi = n;
    while (lo < hi) { int mid = (lo + hi) >> 1; if (batch[mid] <= g) lo = mid + 1; else hi = mid; }
    int end = lo;

    int f = tid & 63, r = tid >> 6;
    float s = 0.f;
    for (int i = start + part * 4 + r; i < end; i += 32)
        s += agg[(size_t)i * 64 + f];

    __shared__ float red[4][64];
    red[r][f] = s;
    __syncthreads();
    if (tid < 64)
        partial[((size_t)g * 8 + part) * 64 + tid] =
            red[0][tid] + red[1][tid] + red[2][tid] + red[3][tid];
}

__global__ __launch_bounds__(64) void k_pool2(
    const float* __restrict__ partial, const int* __restrict__ batch,
    const float* __restrict__ b3, const float* __restrict__ Wlin,
    const float* __restrict__ blin, float* __restrict__ out,
    int n, int fout)
{
    int g = blockIdx.x;
    int tid = threadIdx.x;

    int lo = 0, hi = n;
    while (lo < hi) { int mid = (lo + hi) >> 1; if (batch[mid] < g) lo = mid + 1; else hi = mid; }
    int start = lo;
    hi = n;
    while (lo < hi) { int mid = (lo + hi) >> 1; if (batch[mid] <= g) lo = mid + 1; else hi = mid; }
    int cnt = lo - start;

    __shared__ float pooled[64];
    float v = 0.f;
    #pragma unroll
    for (int p = 0; p < 8; ++p) v += partial[((size_t)g * 8 + p) * 64 + tid];
    pooled[tid] = (cnt > 0) ? (v / (float)cnt + b3[tid]) : 0.f;
    __syncthreads();
    if (tid < fout) {
        float o = blin[tid];
        for (int k = 0; k < 64; ++k) o += pooled[k] * Wlin[k * fout + tid];
        out[(size_t)g * fout + tid] = o;
    }
}

// ================= launcher =================

extern "C" void kernel_launch(void* const* d_in, const int* in_sizes, int n_in,
                              void* d_out, int out_size, void* d_ws, size_t ws_size,
                              hipStream_t stream) {
    const float* x     = (const float*)d_in[0];
    const int*   ei    = (const int*)d_in[1];
    const int*   batch = (const int*)d_in[2];
    const float* W1 = (const float*)d_in[3];
    const float* b1 = (const float*)d_in[4];
    const float* W2 = (const float*)d_in[5];
    const float* b2 = (const float*)d_in[6];
    const float* W3 = (const float*)d_in[7];
    const float* b3 = (const float*)d_in[8];
    const float* Wl = (const float*)d_in[9];
    const float* bl = (const float*)d_in[10];

    int n = in_sizes[0] / 64;
    int E = in_sizes[1] / 2;
    int fout = in_sizes[10];
    int ngraphs = out_size / fout;

    const int* srcp = ei;
    const int* dstp = ei + E;

    // ws layout: agg (f32; bf16 layers 1-2 stored in-place) | t bf16 | partial | cnt | csr
    float* ws   = (float*)d_ws;
    float* agg  = ws;                              // n*64 f32 (also holds bf16 agg)
    u16*   t    = (u16*)(agg + (size_t)n * 64);    // n*64 bf16
    float* partial = (float*)(t + (size_t)n * 64); // 64*8*64
    int* cnt    = (int*)(partial + 64 * 8 * 64);   // n
    int* csr    = cnt + n;                         // n*cap

    size_t fixed = (size_t)n * 64 * 4 + (size_t)n * 64 * 2 +
                   64 * 8 * 64 * 4 + (size_t)n * 4;
    int cap = 64;
    while (cap > 32 && fixed + (size_t)n * cap * 4 > ws_size) cap -= 8;

    int nb_ag = (int)((((long long)(n + 1) / 2) * 64 + 255) / 256);
    int mm_blocks = (((n + 63) / 64 + 7) / 8) * 8;   // multiple of 8
    int fill_chunks = 128;                            // 8 parts x 128 = 1024 blocks

    hipMemsetAsync(cnt, 0, (size_t)n * sizeof(int), stream);
    // t1 = x @ W1 (bf16) + CSR build, overlapped in one dispatch
    k_mm_fill<<<mm_blocks + 8 * fill_chunks, 256, 0, stream>>>(
        x, W1, t, srcp, dstp, cnt, csr, n, E, cap, mm_blocks, fill_chunks);

    // layer 1 aggregate -> bf16 agg (in-place)
    k_aggregate<<<nb_ag, 256, 0, stream>>>(cnt, csr, t, agg, (unsigned int*)agg, 0, n, cap);
    // layer 2
    k_matmul_h<<<mm_blocks, 256, 0, stream>>>((const u16*)agg, W2, b1, t, n);
    k_aggregate<<<nb_ag, 256, 0, stream>>>(cnt, csr, t, agg, (unsigned int*)agg, 0, n, cap);
    // layer 3
    k_matmul_h<<<mm_blocks, 256, 0, stream>>>((const u16*)agg, W3, b2, t, n);
    k_aggregate<<<nb_ag, 256, 0, stream>>>(cnt, csr, t, agg, (unsigned int*)agg, 1, n, cap);

    // pool + linear
    k_pool1<<<ngraphs * 8, 256, 0, stream>>>(agg, batch, partial, n);
    k_pool2<<<ngraphs, 64, 0, stream>>>(partial, batch, b3, Wl, bl, (float*)d_out, n, fout);
}

// Round 11
// 291.532 us; speedup vs baseline: 1.3345x; 1.0186x over previous
//
#include <hip/hip_runtime.h>

#define FDIM 64

typedef unsigned short u16;

__device__ __forceinline__ u16 f2bf(float x) {          // RNE f32->bf16
    unsigned int u = __float_as_uint(x);
    return (u16)((u + 0x7fff + ((u >> 16) & 1)) >> 16);
}
__device__ __forceinline__ float bf2f(u16 h) {
    return __uint_as_float(((unsigned int)h) << 16);
}
__device__ __forceinline__ float2 up2(unsigned int u) { // 2 packed bf16 -> 2 f32
    float2 r;
    r.x = __uint_as_float(u << 16);
    r.y = __uint_as_float(u & 0xffff0000u);
    return r;
}

// ========= dense tile: t[64 rows] = act(ain + bias) @ W  (bf16 out) =========
// Known-good 52-VGPR structure: A staged to LDS f32, W in LDS.

template <bool BF16IN>
__device__ __forceinline__ void mm_tile64(
    const void* __restrict__ ain, const float* __restrict__ bias, int do_relu,
    u16* __restrict__ t, int n, int blk,
    float (*__restrict__ As)[FDIM + 1], float* __restrict__ Ws)
{
    int tid = threadIdx.x;
    int r0 = blk * 64;

    #pragma unroll
    for (int i = 0; i < 4; ++i) {
        int idx = tid + 256 * i;
        int r = idx >> 4;
        int kq = idx & 15;
        float4 v = make_float4(0.f, 0.f, 0.f, 0.f);
        int R = r0 + r;
        if (R < n) {
            if (BF16IN) {
                ushort4 h = ((const ushort4*)ain)[(size_t)R * 16 + kq];
                v.x = bf2f(h.x); v.y = bf2f(h.y); v.z = bf2f(h.z); v.w = bf2f(h.w);
            } else {
                v = ((const float4*)ain)[(size_t)R * 16 + kq];
            }
            if (bias != nullptr) {
                float4 b = ((const float4*)bias)[kq];
                v.x += b.x; v.y += b.y; v.z += b.z; v.w += b.w;
            }
            if (do_relu) {
                v.x = fmaxf(v.x, 0.f); v.y = fmaxf(v.y, 0.f);
                v.z = fmaxf(v.z, 0.f); v.w = fmaxf(v.w, 0.f);
            }
        }
        As[r][kq * 4 + 0] = v.x;
        As[r][kq * 4 + 1] = v.y;
        As[r][kq * 4 + 2] = v.z;
        As[r][kq * 4 + 3] = v.w;
    }
    __syncthreads();

    int rq = tid >> 4;   // rows rq*4..+3
    int cq = tid & 15;   // cols cq*4..+3
    float acc[4][4];
    #pragma unroll
    for (int i = 0; i < 4; ++i)
        #pragma unroll
        for (int j = 0; j < 4; ++j) acc[i][j] = 0.f;

    const float4* Ws4 = (const float4*)Ws;
    #pragma unroll 4
    for (int k = 0; k < FDIM; ++k) {
        float4 w = Ws4[k * 16 + cq];
        float a[4];
        #pragma unroll
        for (int i = 0; i < 4; ++i) a[i] = As[rq * 4 + i][k];
        #pragma unroll
        for (int i = 0; i < 4; ++i) {
            acc[i][0] = fmaf(a[i], w.x, acc[i][0]);
            acc[i][1] = fmaf(a[i], w.y, acc[i][1]);
            acc[i][2] = fmaf(a[i], w.z, acc[i][2]);
            acc[i][3] = fmaf(a[i], w.w, acc[i][3]);
        }
    }

    #pragma unroll
    for (int i = 0; i < 4; ++i) {
        int R = r0 + rq * 4 + i;
        if (R < n) {
            ushort4 o;
            o.x = f2bf(acc[i][0]); o.y = f2bf(acc[i][1]);
            o.z = f2bf(acc[i][2]); o.w = f2bf(acc[i][3]);
            ((ushort4*)t)[(size_t)R * 16 + cq] = o;
        }
    }
}

// layers 2/3: A = bf16 agg
__global__ __launch_bounds__(256) void k_matmul_h(
    const u16* __restrict__ ain, const float* __restrict__ Wm,
    const float* __restrict__ bias, u16* __restrict__ t, int n)
{
    __shared__ float As[64][FDIM + 1];
    __shared__ float Ws[FDIM * FDIM];
    int tid = threadIdx.x;
    #pragma unroll
    for (int i = 0; i < 4; ++i)
        ((float4*)Ws)[tid + 256 * i] = ((const float4*)Wm)[tid + 256 * i];
    mm_tile64<true>(ain, bias, 1, t, n, blockIdx.x, As, Ws);
}

// ===== combined dispatch: matmul1 blocks + XCD-partitioned CSR-fill blocks ==

__global__ __launch_bounds__(256) void k_mm_fill(
    const float* __restrict__ x, const float* __restrict__ W1,
    u16* __restrict__ t,
    const int* __restrict__ src, const int* __restrict__ dst,
    int* __restrict__ cnt, int* __restrict__ csr,
    int n, int E, int cap, int mm_blocks, int fill_chunks)
{
    __shared__ float As[64][FDIM + 1];
    __shared__ float Ws[FDIM * FDIM];

    if ((int)blockIdx.x < mm_blocks) {
        int tid = threadIdx.x;
        #pragma unroll
        for (int i = 0; i < 4; ++i)
            ((float4*)Ws)[tid + 256 * i] = ((const float4*)W1)[tid + 256 * i];
        mm_tile64<false>(x, nullptr, 0, t, n, blockIdx.x, As, Ws);
        return;
    }
    // fill: partition dst range by XCD (blockIdx%8 round-robin; mm_blocks%8==0)
    int gb = blockIdx.x - mm_blocks;
    int part = blockIdx.x & 7;
    int chunk = gb >> 3;
    int psz = n >> 3;
    int lo = psz * part;
    int hi = (part == 7) ? n : lo + psz;
    int per = (E + fill_chunks - 1) / fill_chunks;
    int e1 = chunk * per + per; if (e1 > E) e1 = E;
    for (int e = chunk * per + threadIdx.x; e < e1; e += 256) {
        int d = dst[e];
        if (d >= lo && d < hi) {
            int p = atomicAdd(&cnt[d], 1);
            if (p < cap) csr[(size_t)d * cap + p] = src[e];
        }
    }
}

// == aggregate: out[i] = di*(di*t_i + sum_j dj*t_j);  di = rsqrt(deg_i+1) ==
// 4 nodes per wave: 16-lane group per node, lane = uint2 (4 bf16 feats).
// Each gather = 16 lanes x 8 B = 128 B coalesced row; 4 streams x 8-deep
// batches = 32 loads in flight per wave.

__global__ __launch_bounds__(256) void k_aggregate(
    const int* __restrict__ cnt, const int* __restrict__ csr,
    const u16* __restrict__ t, float* __restrict__ aggf,
    uint2* __restrict__ aggh, int outf32, int n, int cap)
{
    int tid = threadIdx.x;
    long long gw = ((long long)blockIdx.x * 256 + tid) >> 6;
    int lane = tid & 63;
    int sub = lane >> 4;      // node within wave (0..3)
    int li  = lane & 15;      // uint2 index within row (0..15)
    long long il = gw * 4 + sub;
    if (il >= n) return;
    int i = (int)il;

    int deg = cnt[i];
    float di = rsqrtf((float)deg + 1.0f);
    int m = deg < cap ? deg : cap;

    const uint2* tu = (const uint2*)t;
    uint2 sp = tu[(size_t)i * 16 + li];
    float2 s0 = up2(sp.x), s1 = up2(sp.y);
    float4 A0 = make_float4(s0.x * di, s0.y * di, s1.x * di, s1.y * di);
    float4 A1 = make_float4(0.f, 0.f, 0.f, 0.f);
    float4 A2 = make_float4(0.f, 0.f, 0.f, 0.f);
    float4 A3 = make_float4(0.f, 0.f, 0.f, 0.f);

    const int* row = csr + (size_t)i * cap;
    int nbase = sub << 4;

    for (int c0 = 0; c0 < m; c0 += 16) {
        int cm = m - c0; if (cm > 16) cm = 16;
        int sv = 0; float dvv = 0.f;
        if (li < cm) { sv = row[c0 + li]; dvv = rsqrtf((float)cnt[sv] + 1.0f); }
        int k = 0;
        for (; k + 8 <= cm; k += 8) {
            int jv[8]; float dj[8]; uint2 v[8];
            #pragma unroll
            for (int u = 0; u < 8; ++u) {
                jv[u] = __shfl(sv, nbase + k + u);
                dj[u] = __shfl(dvv, nbase + k + u);
            }
            #pragma unroll
            for (int u = 0; u < 8; ++u) v[u] = tu[(size_t)jv[u] * 16 + li];
            #pragma unroll
            for (int u = 0; u < 8; ++u) {
                float2 x0 = up2(v[u].x), x1 = up2(v[u].y);
                float4* Ap = (u & 3) == 0 ? &A0 : (u & 3) == 1 ? &A1 :
                             (u & 3) == 2 ? &A2 : &A3;
                Ap->x = fmaf(x0.x, dj[u], Ap->x);
                Ap->y = fmaf(x0.y, dj[u], Ap->y);
                Ap->z = fmaf(x1.x, dj[u], Ap->z);
                Ap->w = fmaf(x1.y, dj[u], Ap->w);
            }
        }
        if (k + 4 <= cm) {
            int jv[4]; float dj[4]; uint2 v[4];
            #pragma unroll
            for (int u = 0; u < 4; ++u) {
                jv[u] = __shfl(sv, nbase + k + u);
                dj[u] = __shfl(dvv, nbase + k + u);
            }
            #pragma unroll
            for (int u = 0; u < 4; ++u) v[u] = tu[(size_t)jv[u] * 16 + li];
            #pragma unroll
            for (int u = 0; u < 4; ++u) {
                float2 x0 = up2(v[u].x), x1 = up2(v[u].y);
                float4* Ap = u == 0 ? &A0 : u == 1 ? &A1 : u == 2 ? &A2 : &A3;
                Ap->x = fmaf(x0.x, dj[u], Ap->x);
                Ap->y = fmaf(x0.y, dj[u], Ap->y);
                Ap->z = fmaf(x1.x, dj[u], Ap->z);
                Ap->w = fmaf(x1.y, dj[u], Ap->w);
            }
            k += 4;
        }
        for (; k < cm; ++k) {
            int j = __shfl(sv, nbase + k);
            float dj = __shfl(dvv, nbase + k);
            uint2 vv = tu[(size_t)j * 16 + li];
            float2 x0 = up2(vv.x), x1 = up2(vv.y);
            A0.x = fmaf(x0.x, dj, A0.x);
            A0.y = fmaf(x0.y, dj, A0.y);
            A0.z = fmaf(x1.x, dj, A0.z);
            A0.w = fmaf(x1.y, dj, A0.w);
        }
    }

    float4 O;
    O.x = ((A0.x + A1.x) + (A2.x + A3.x)) * di;
    O.y = ((A0.y + A1.y) + (A2.y + A3.y)) * di;
    O.z = ((A0.z + A1.z) + (A2.z + A3.z)) * di;
    O.w = ((A0.w + A1.w) + (A2.w + A3.w)) * di;
    if (outf32) {
        ((float4*)aggf)[(size_t)i * 16 + li] = O;
    } else {
        uint2 pk;
        pk.x = ((unsigned int)f2bf(O.x)) | (((unsigned int)f2bf(O.y)) << 16);
        pk.y = ((unsigned int)f2bf(O.z)) | (((unsigned int)f2bf(O.w)) << 16);
        aggh[(size_t)i * 16 + li] = pk;
    }
}

// ================= pool =================

__global__ __launch_bounds__(256) void k_pool1(
    const float* __restrict__ agg, const int* __restrict__ batch,
    float* __restrict__ partial, int n)
{
    int g = blockIdx.x >> 3;
    int part = blockIdx.x & 7;
    int tid = threadIdx.x;

    int lo = 0, hi = n;
    while (lo < hi) { int mid = (lo + hi) >> 1; if (batch[mid] < g) lo = mid + 1; else hi = mid; }
    int start = lo;
    hi = n;
    while (lo < hi) { int mid = (lo + hi) >> 1; if (batch[mid] <= g) lo = mid + 1; else hi = mid; }
    int end = lo;

    int f = tid & 63, r = tid >> 6;
    float s = 0.f;
    for (int i = start + part * 4 + r; i < end; i += 32)
        s += agg[(size_t)i * 64 + f];

    __shared__ float red[4][64];
    red[r][f] = s;
    __syncthreads();
    if (tid < 64)
        partial[((size_t)g * 8 + part) * 64 + tid] =
            red[0][tid] + red[1][tid] + red[2][tid] + red[3][tid];
}

__global__ __launch_bounds__(64) void k_pool2(
    const float* __restrict__ partial, const int* __restrict__ batch,
    const float* __restrict__ b3, const float* __restrict__ Wlin,
    const float* __restrict__ blin, float* __restrict__ out,
    int n, int fout)
{
    int g = blockIdx.x;
    int tid = threadIdx.x;

    int lo = 0, hi = n;
    while (lo < hi) { int mid = (lo + hi) >> 1; if (batch[mid] < g) lo = mid + 1; else hi = mid; }
    int start = lo;
    hi = n;
    while (lo < hi) { int mid = (lo + hi) >> 1; if (batch[mid] <= g) lo = mid + 1; else hi = mid; }
    int cnt = lo - start;

    __shared__ float pooled[64];
    float v = 0.f;
    #pragma unroll
    for (int p = 0; p < 8; ++p) v += partial[((size_t)g * 8 + p) * 64 + tid];
    pooled[tid] = (cnt > 0) ? (v / (float)cnt + b3[tid]) : 0.f;
    __syncthreads();
    if (tid < fout) {
        float o = blin[tid];
        for (int k = 0; k < 64; ++k) o += pooled[k] * Wlin[k * fout + tid];
        out[(size_t)g * fout + tid] = o;
    }
}

// ================= launcher =================

extern "C" void kernel_launch(void* const* d_in, const int* in_sizes, int n_in,
                              void* d_out, int out_size, void* d_ws, size_t ws_size,
                              hipStream_t stream) {
    const float* x     = (const float*)d_in[0];
    const int*   ei    = (const int*)d_in[1];
    const int*   batch = (const int*)d_in[2];
    const float* W1 = (const float*)d_in[3];
    const float* b1 = (const float*)d_in[4];
    const float* W2 = (const float*)d_in[5];
    const float* b2 = (const float*)d_in[6];
    const float* W3 = (const float*)d_in[7];
    const float* b3 = (const float*)d_in[8];
    const float* Wl = (const float*)d_in[9];
    const float* bl = (const float*)d_in[10];

    int n = in_sizes[0] / 64;
    int E = in_sizes[1] / 2;
    int fout = in_sizes[10];
    int ngraphs = out_size / fout;

    const int* srcp = ei;
    const int* dstp = ei + E;

    // ws layout: agg (f32; bf16 layers 1-2 in-place) | t bf16 | partial | cnt | csr
    float* ws   = (float*)d_ws;
    float* agg  = ws;                              // n*64 f32 (also holds bf16 agg)
    u16*   t    = (u16*)(agg + (size_t)n * 64);    // n*64 bf16
    float* partial = (float*)(t + (size_t)n * 64); // 64*8*64
    int* cnt    = (int*)(partial + 64 * 8 * 64);   // n
    int* csr    = cnt + n;                         // n*cap

    size_t fixed = (size_t)n * 64 * 4 + (size_t)n * 64 * 2 +
                   64 * 8 * 64 * 4 + (size_t)n * 4;
    int cap = 64;
    while (cap > 32 && fixed + (size_t)n * cap * 4 > ws_size) cap -= 8;

    int nb_ag = (int)((((long long)(n + 3) / 4) * 64 + 255) / 256);
    int mm_blocks = (((n + 63) / 64 + 7) / 8) * 8;   // multiple of 8
    int fill_chunks = 128;                            // 8 parts x 128 = 1024 blocks

    hipMemsetAsync(cnt, 0, (size_t)n * sizeof(int), stream);
    // t1 = x @ W1 (bf16) + CSR build, overlapped in one dispatch
    k_mm_fill<<<mm_blocks + 8 * fill_chunks, 256, 0, stream>>>(
        x, W1, t, srcp, dstp, cnt, csr, n, E, cap, mm_blocks, fill_chunks);

    // layer 1 aggregate -> bf16 agg (in-place)
    k_aggregate<<<nb_ag, 256, 0, stream>>>(cnt, csr, t, agg, (uint2*)agg, 0, n, cap);
    // layer 2
    k_matmul_h<<<mm_blocks, 256, 0, stream>>>((const u16*)agg, W2, b1, t, n);
    k_aggregate<<<nb_ag, 256, 0, stream>>>(cnt, csr, t, agg, (uint2*)agg, 0, n, cap);
    // layer 3
    k_matmul_h<<<mm_blocks, 256, 0, stream>>>((const u16*)agg, W3, b2, t, n);
    k_aggregate<<<nb_ag, 256, 0, stream>>>(cnt, csr, t, agg, (uint2*)agg, 1, n, cap);

    // pool + linear
    k_pool1<<<ngraphs * 8, 256, 0, stream>>>(agg, batch, partial, n);
    k_pool2<<<ngraphs, 64, 0, stream>>>(partial, batch, b3, Wl, bl, (float*)d_out, n, fout);
}